// Round 4
// baseline (28.744 us; speedup 1.0000x reference)
//
#include <hip/hip_runtime.h>
#include <hip/hip_bf16.h>

// JSSP dynamic embedding update. OUTPUT IS FLOAT32 (reference returns f32;
// round-3 probe confirmed: 2-byte store to d_out[0] read back as denormal~0).
// Shapes: bs=128, M=64, O=4096, J=64, E=256. SCALE=1000.
// For job j of batch b, o = next_op[b,j]:
//   a = max(lbs[b,o]-time[b],0)/1000 ; r = is_ready[b,o]
//   acc[e] = sum_m [busy[b,m]>time[b] ? 0 : proc[b,m,o]/1000] * emb[b,m,e]
//   out_k[b,j,e] = a*Wn[0,k*256+e] + r*Wn[1,k*256+e] + We[k]*acc[e]

#define BS 128
#define MM 64
#define OO 4096
#define JJ 64
#define EE 256
#define JH 16   // jobs per block (4 blocks per batch)

__global__ __launch_bounds__(256) void jssp_kernel(
    const float* __restrict__ lbs,       // [BS,OO]
    const float* __restrict__ time_,     // [BS]
    const float* __restrict__ isr,       // [BS,OO]
    const float* __restrict__ proc,      // [BS,MM,OO]
    const float* __restrict__ busy,      // [BS,MM]
    const float* __restrict__ emb,       // [BS,MM,EE]
    const float* __restrict__ Wn,        // [2,768]
    const float* __restrict__ We,        // [3]
    const int*   __restrict__ nop,       // [BS,JJ]
    float* __restrict__ out)             // 3 x [BS,JJ,EE] concatenated, f32
{
    __shared__ float S[JH][MM];    // masked, scaled job_proc
    __shared__ float fmul[MM];     // free-machine multiplier (0 or 1e-3)
    __shared__ float aj[JH];
    __shared__ float rj[JH];

    const int b  = blockIdx.x >> 2;
    const int jh = blockIdx.x & 3;
    const int t  = threadIdx.x;    // 0..255 == e
    const float tb = time_[b];

    if (t < MM) fmul[t] = (busy[b * MM + t] > tb) ? 0.0f : 1e-3f;
    if (t < JH) {
        const int o = nop[b * JJ + jh * JH + t];
        aj[t] = fmaxf(lbs[b * OO + o] - tb, 0.0f) * 1e-3f;
        rj[t] = isr[b * OO + o];
    }
    __syncthreads();

    // Gather S[jj][m] = proc[b,m,o(jj)] * fmul[m]; JH*64 entries, 4/thread.
    #pragma unroll
    for (int it = 0; it < (JH * MM) / 256; ++it) {
        const int idx = it * 256 + t;
        const int jj = idx >> 6;
        const int m  = idx & 63;
        const int o  = nop[b * JJ + jh * JH + jj];
        S[jj][m] = proc[(size_t)(b * MM + m) * OO + (size_t)o] * fmul[m];
    }

    // Stage emb column e in registers (static indexing -> stays in VGPRs).
    float ecol[MM];
    #pragma unroll
    for (int m = 0; m < MM; ++m)
        ecol[m] = emb[(size_t)(b * MM + m) * EE + (size_t)t];

    // Per-thread node-linear constants (column e of the three E-slices).
    const float w0a = Wn[t],            w1a = Wn[768 + t];
    const float w0b = Wn[EE + t],       w1b = Wn[768 + EE + t];
    const float w0c = Wn[2 * EE + t],   w1c = Wn[768 + 2 * EE + t];
    const float we0 = We[0], we1 = We[1], we2 = We[2];

    __syncthreads();   // S fully written

    const size_t SZ   = (size_t)BS * JJ * EE;          // 2097152
    const size_t base = (size_t)(b * JJ + jh * JH) * EE + (size_t)t;

    for (int jj = 0; jj < JH; ++jj) {
        float acc = 0.0f;
        #pragma unroll
        for (int m = 0; m < MM; ++m)
            acc = fmaf(S[jj][m], ecol[m], acc);
        const float a = aj[jj];
        const float r = rj[jj];
        const size_t off = base + (size_t)jj * EE;
        out[off]          = fmaf(a, w0a, fmaf(r, w1a, we0 * acc));
        out[SZ + off]     = fmaf(a, w0b, fmaf(r, w1b, we1 * acc));
        out[2 * SZ + off] = fmaf(a, w0c, fmaf(r, w1c, we2 * acc));
    }
}

extern "C" void kernel_launch(void* const* d_in, const int* in_sizes, int n_in,
                              void* d_out, int out_size, void* d_ws, size_t ws_size,
                              hipStream_t stream) {
    const float* lbs   = (const float*)d_in[0];
    const float* time_ = (const float*)d_in[1];
    const float* isr   = (const float*)d_in[2];
    const float* proc  = (const float*)d_in[3];
    const float* busy  = (const float*)d_in[4];
    const float* emb   = (const float*)d_in[5];
    const float* Wn    = (const float*)d_in[6];
    const float* We    = (const float*)d_in[7];
    const int*   nop   = (const int*)d_in[8];
    float* out = (float*)d_out;

    jssp_kernel<<<dim3(BS * (JJ / JH)), dim3(256), 0, stream>>>(
        lbs, time_, isr, proc, busy, emb, Wn, We, nop, out);
}

// Round 5
// 21.974 us; speedup vs baseline: 1.3081x; 1.3081x over previous
//
#include <hip/hip_runtime.h>
#include <hip/hip_bf16.h>

// JSSP dynamic embedding update. f32 in / f32 out.
// Shapes: bs=128, M=64, O=4096, J=64, E=256. SCALE=1000.
// For job j of batch b, o = next_op[b,j]:
//   a = max(lbs[b,o]-time[b],0)/1000 ; r = is_ready[b,o]
//   acc[e] = sum_m [busy[b,m]>time[b] ? 0 : proc[b,m,o]/1000] * emb[b,m,e]
//   out_k[b,j,e] = a*Wn[0,k*256+e] + r*Wn[1,k*256+e] + We[k]*acc[e]
//
// Structure: 1024 blocks = 128 batches x 8 job-octets, 256 threads (t = e).
// XCD-aware remap: all 8 sibling blocks of a batch -> same XCD, adjacent
// dispatch slots => emb[b] (64KB) fetched once into that XCD's L2.

#define BS 128
#define MM 64
#define OO 4096
#define JJ 64
#define EE 256
#define JH 8    // jobs per block (8 blocks per batch)

__global__ __launch_bounds__(256) void jssp_kernel(
    const float* __restrict__ lbs,       // [BS,OO]
    const float* __restrict__ time_,     // [BS]
    const float* __restrict__ isr,       // [BS,OO]
    const float* __restrict__ proc,      // [BS,MM,OO]
    const float* __restrict__ busy,      // [BS,MM]
    const float* __restrict__ emb,       // [BS,MM,EE]
    const float* __restrict__ Wn,        // [2,768]
    const float* __restrict__ We,        // [3]
    const int*   __restrict__ nop,       // [BS,JJ]
    float* __restrict__ out)             // 3 x [BS,JJ,EE] concatenated, f32
{
    __shared__ float S[JH][MM];    // masked, scaled job_proc
    __shared__ float fmul[MM];     // free-machine multiplier (0 or 1e-3)
    __shared__ float aj[JH];
    __shared__ float rj[JH];

    // XCD-aware bijective remap (8 XCDs, grid 1024 % 8 == 0):
    const int hw  = blockIdx.x;
    const int xcd = hw & 7;
    const int k   = hw >> 3;            // 0..127 within-XCD order
    const int b   = xcd * 16 + (k >> 3);// 16 batches per XCD
    const int jh  = k & 7;              // sibling blocks adjacent in k

    const int t  = threadIdx.x;    // 0..255 == e
    const float tb = time_[b];

    if (t < MM) fmul[t] = (busy[b * MM + t] > tb) ? 0.0f : 1e-3f;
    if (t < JH) {
        const int o = nop[b * JJ + jh * JH + t];
        aj[t] = fmaxf(lbs[b * OO + o] - tb, 0.0f) * 1e-3f;
        rj[t] = isr[b * OO + o];
    }
    __syncthreads();

    // Gather S[jj][m] = proc[b,m,o(jj)] * fmul[m]; JH*MM = 512 entries.
    {
        const int idx = t;                   // 2 per thread
        #pragma unroll
        for (int it = 0; it < (JH * MM) / 256; ++it) {
            const int id = it * 256 + idx;
            const int jj = id >> 6;
            const int m  = id & 63;
            const int o  = nop[b * JJ + jh * JH + jj];
            S[jj][m] = proc[(size_t)(b * MM + m) * OO + (size_t)o] * fmul[m];
        }
    }

    // Stage emb column e in registers (static indexing -> VGPRs).
    float ecol[MM];
    #pragma unroll
    for (int m = 0; m < MM; ++m)
        ecol[m] = emb[(size_t)(b * MM + m) * EE + (size_t)t];

    // Per-thread node-linear constants (column e of the three E-slices).
    const float w0a = Wn[t],            w1a = Wn[768 + t];
    const float w0b = Wn[EE + t],       w1b = Wn[768 + EE + t];
    const float w0c = Wn[2 * EE + t],   w1c = Wn[768 + 2 * EE + t];
    const float we0 = We[0], we1 = We[1], we2 = We[2];

    __syncthreads();   // S fully written

    const size_t SZ   = (size_t)BS * JJ * EE;          // 2097152
    const size_t base = (size_t)(b * JJ + jh * JH) * EE + (size_t)t;

    for (int jj = 0; jj < JH; ++jj) {
        const float4* S4 = reinterpret_cast<const float4*>(&S[jj][0]);
        float acc = 0.0f;
        #pragma unroll
        for (int m4 = 0; m4 < MM / 4; ++m4) {
            const float4 s = S4[m4];           // uniform-address broadcast
            acc = fmaf(s.x, ecol[4 * m4 + 0], acc);
            acc = fmaf(s.y, ecol[4 * m4 + 1], acc);
            acc = fmaf(s.z, ecol[4 * m4 + 2], acc);
            acc = fmaf(s.w, ecol[4 * m4 + 3], acc);
        }
        const float a = aj[jj];
        const float r = rj[jj];
        const size_t off = base + (size_t)jj * EE;
        out[off]          = fmaf(a, w0a, fmaf(r, w1a, we0 * acc));
        out[SZ + off]     = fmaf(a, w0b, fmaf(r, w1b, we1 * acc));
        out[2 * SZ + off] = fmaf(a, w0c, fmaf(r, w1c, we2 * acc));
    }
}

extern "C" void kernel_launch(void* const* d_in, const int* in_sizes, int n_in,
                              void* d_out, int out_size, void* d_ws, size_t ws_size,
                              hipStream_t stream) {
    const float* lbs   = (const float*)d_in[0];
    const float* time_ = (const float*)d_in[1];
    const float* isr   = (const float*)d_in[2];
    const float* proc  = (const float*)d_in[3];
    const float* busy  = (const float*)d_in[4];
    const float* emb   = (const float*)d_in[5];
    const float* Wn    = (const float*)d_in[6];
    const float* We    = (const float*)d_in[7];
    const int*   nop   = (const int*)d_in[8];
    float* out = (float*)d_out;

    jssp_kernel<<<dim3(BS * (JJ / JH)), dim3(256), 0, stream>>>(
        lbs, time_, isr, proc, busy, emb, Wn, We, nop, out);
}

// Round 6
// 21.859 us; speedup vs baseline: 1.3150x; 1.0053x over previous
//
#include <hip/hip_runtime.h>
#include <hip/hip_bf16.h>

// JSSP dynamic embedding update. f32 in / f32 out.
// Shapes: bs=128, M=64, O=4096, J=64, E=256. SCALE=1000.
// For job j of batch b, o = next_op[b,j]:
//   a = max(lbs[b,o]-time[b],0)/1000 ; r = is_ready[b,o]
//   acc[e] = sum_m [busy[b,m]>time[b] ? 0 : proc[b,m,o]/1000] * emb[b,m,e]
//   out_k[b,j,e] = a*Wn[0,k*256+e] + r*Wn[1,k*256+e] + We[k]*acc[e]
//
// v6: single-barrier structure. All global loads (proc gather + busy mask +
// aj/rj gathers + 64 emb column loads) issue with no intervening barrier;
// the one __syncthreads() drains everything once. Busy-mask applied inline
// (no fmul[] LDS stage). __launch_bounds__(256,4) caps VGPR at 128 ->
// 4 blocks/CU. XCD remap keeps a batch's 8 sibling blocks on one XCD.

#define BS 128
#define MM 64
#define OO 4096
#define JJ 64
#define EE 256
#define JH 8    // jobs per block (8 blocks per batch)

__global__ __launch_bounds__(256, 4) void jssp_kernel(
    const float* __restrict__ lbs,       // [BS,OO]
    const float* __restrict__ time_,     // [BS]
    const float* __restrict__ isr,       // [BS,OO]
    const float* __restrict__ proc,      // [BS,MM,OO]
    const float* __restrict__ busy,      // [BS,MM]
    const float* __restrict__ emb,       // [BS,MM,EE]
    const float* __restrict__ Wn,        // [2,768]
    const float* __restrict__ We,        // [3]
    const int*   __restrict__ nop,       // [BS,JJ]
    float* __restrict__ out)             // 3 x [BS,JJ,EE] concatenated, f32
{
    __shared__ float S[JH][MM];    // masked, scaled job_proc
    __shared__ float aj[JH];
    __shared__ float rj[JH];

    // XCD-aware bijective remap (8 XCDs, grid 1024 % 8 == 0):
    const int hw  = blockIdx.x;
    const int xcd = hw & 7;
    const int k   = hw >> 3;             // 0..127 within-XCD order
    const int b   = xcd * 16 + (k >> 3); // 16 batches per XCD
    const int jh  = k & 7;               // sibling blocks adjacent in k

    const int t  = threadIdx.x;    // 0..255 == e
    const float tb = time_[b];

    // ---- issue ALL global loads before any barrier ----

    // proc gather (+ per-element busy mask), 2 elements/thread:
    int   gjj[2], gm[2];
    float gv[2], gbz[2];
    #pragma unroll
    for (int it = 0; it < 2; ++it) {
        const int id = it * 256 + t;
        const int jj = id >> 6;
        const int m  = id & 63;
        const int o  = nop[b * JJ + jh * JH + jj];
        gjj[it] = jj; gm[it] = m;
        gv[it]  = proc[(size_t)(b * MM + m) * OO + (size_t)o];
        gbz[it] = busy[b * MM + m];
    }

    // aj/rj gathers (8 lanes):
    float al = 0.0f, rl = 0.0f;
    if (t < JH) {
        const int o = nop[b * JJ + jh * JH + t];
        al = lbs[b * OO + o];
        rl = isr[b * OO + o];
    }

    // emb column e -> registers (static indexing -> VGPRs):
    float ecol[MM];
    #pragma unroll
    for (int m = 0; m < MM; ++m)
        ecol[m] = emb[(size_t)(b * MM + m) * EE + (size_t)t];

    // node-linear constants (column e of the three E-slices):
    const float w0a = Wn[t],            w1a = Wn[768 + t];
    const float w0b = Wn[EE + t],       w1b = Wn[768 + EE + t];
    const float w0c = Wn[2 * EE + t],   w1c = Wn[768 + 2 * EE + t];
    const float we0 = We[0], we1 = We[1], we2 = We[2];

    // ---- LDS writes, then the single barrier ----
    #pragma unroll
    for (int it = 0; it < 2; ++it)
        S[gjj[it]][gm[it]] = (gbz[it] > tb) ? 0.0f : gv[it] * 1e-3f;
    if (t < JH) {
        aj[t] = fmaxf(al - tb, 0.0f) * 1e-3f;
        rj[t] = rl;
    }
    __syncthreads();

    // ---- compute + store ----
    const size_t SZ   = (size_t)BS * JJ * EE;          // 2097152
    const size_t base = (size_t)(b * JJ + jh * JH) * EE + (size_t)t;

    for (int jj = 0; jj < JH; ++jj) {
        const float4* S4 = reinterpret_cast<const float4*>(&S[jj][0]);
        float acc = 0.0f;
        #pragma unroll
        for (int m4 = 0; m4 < MM / 4; ++m4) {
            const float4 s = S4[m4];           // uniform-address broadcast
            acc = fmaf(s.x, ecol[4 * m4 + 0], acc);
            acc = fmaf(s.y, ecol[4 * m4 + 1], acc);
            acc = fmaf(s.z, ecol[4 * m4 + 2], acc);
            acc = fmaf(s.w, ecol[4 * m4 + 3], acc);
        }
        const float a = aj[jj];
        const float r = rj[jj];
        const size_t off = base + (size_t)jj * EE;
        out[off]          = fmaf(a, w0a, fmaf(r, w1a, we0 * acc));
        out[SZ + off]     = fmaf(a, w0b, fmaf(r, w1b, we1 * acc));
        out[2 * SZ + off] = fmaf(a, w0c, fmaf(r, w1c, we2 * acc));
    }
}

extern "C" void kernel_launch(void* const* d_in, const int* in_sizes, int n_in,
                              void* d_out, int out_size, void* d_ws, size_t ws_size,
                              hipStream_t stream) {
    const float* lbs   = (const float*)d_in[0];
    const float* time_ = (const float*)d_in[1];
    const float* isr   = (const float*)d_in[2];
    const float* proc  = (const float*)d_in[3];
    const float* busy  = (const float*)d_in[4];
    const float* emb   = (const float*)d_in[5];
    const float* Wn    = (const float*)d_in[6];
    const float* We    = (const float*)d_in[7];
    const int*   nop   = (const int*)d_in[8];
    float* out = (float*)d_out;

    jssp_kernel<<<dim3(BS * (JJ / JH)), dim3(256), 0, stream>>>(
        lbs, time_, isr, proc, busy, emb, Wn, We, nop, out);
}

// Round 7
// 21.265 us; speedup vs baseline: 1.3517x; 1.0279x over previous
//
#include <hip/hip_runtime.h>

// JSSP dynamic embedding update. f32 in / f32 out.
// Shapes: bs=128, M=64, O=4096, J=64, E=256. SCALE=1000.
// For job j of batch b, o = next_op[b,j]:
//   a = max(lbs[b,o]-time[b],0)/1000 ; r = is_ready[b,o]
//   acc[e] = sum_m [busy[b,m]>time[b] ? 0 : proc[b,m,o]/1000] * emb[b,m,e]
//   out_k[b,j,e] = a*Wn[0,k*256+e] + r*Wn[1,k*256+e] + We[k]*acc[e]
//
// v7: occupancy push (24 waves/CU via chunked emb staging, VGPR ~80,
// __launch_bounds__(256,6)) + DRAM-local gather mapping (wave-instr covers
// 8 rows x 8 jobs instead of 64 strided rows) + pre-barrier emb prefetch.

#define BS 128
#define MM 64
#define OO 4096
#define JJ 64
#define EE 256
#define JH 8     // jobs per block (8 blocks per batch)
#define SP 68    // padded LDS row (16B-aligned rows, conflict-light writes)

__global__ __launch_bounds__(256, 6) void jssp_kernel(
    const float* __restrict__ lbs,       // [BS,OO]
    const float* __restrict__ time_,     // [BS]
    const float* __restrict__ isr,       // [BS,OO]
    const float* __restrict__ proc,      // [BS,MM,OO]
    const float* __restrict__ busy,      // [BS,MM]
    const float* __restrict__ emb,       // [BS,MM,EE]
    const float* __restrict__ Wn,        // [2,768]
    const float* __restrict__ We,        // [3]
    const int*   __restrict__ nop,       // [BS,JJ]
    float* __restrict__ out)             // 3 x [BS,JJ,EE] concatenated, f32
{
    __shared__ float S[JH][SP];
    __shared__ float aj[JH], rj[JH];

    // XCD-aware bijective remap (8 XCDs, grid 1024 % 8 == 0):
    const int hw  = blockIdx.x;
    const int xcd = hw & 7;
    const int k   = hw >> 3;
    const int b   = xcd * 16 + (k >> 3);
    const int jh  = k & 7;
    const int t   = threadIdx.x;          // 0..255 == e
    const float tb = time_[b];

    // ---- proc gather: 2/thread; wave-instr covers 8 rows x 8 jobs ----
    float gv[2], gbz[2];
    int   gjj[2], gm[2];
    #pragma unroll
    for (int it = 0; it < 2; ++it) {
        const int id = it * 256 + t;
        const int jj = id & 7;            // 0..7
        const int m  = id >> 3;           // 0..63
        const int o  = nop[b * JJ + jh * JH + jj];
        gjj[it] = jj; gm[it] = m;
        gv[it]  = proc[(size_t)(b * MM + m) * OO + (size_t)o];
        gbz[it] = busy[b * MM + m];
    }

    // aj/rj gathers (8 lanes of wave 0):
    float al = 0.0f, rl = 0.0f;
    if (t < JH) {
        const int o = nop[b * JJ + jh * JH + t];
        al = lbs[b * OO + o];
        rl = isr[b * OO + o];
    }

    // node-linear constants (column e of the three E-slices):
    const float w0a = Wn[t],            w1a = Wn[768 + t];
    const float w0b = Wn[EE + t],       w1b = Wn[768 + EE + t];
    const float w0c = Wn[2 * EE + t],   w1c = Wn[768 + 2 * EE + t];
    const float we0 = We[0], we1 = We[1], we2 = We[2];

    // emb chunks 0,1 prefetch BEFORE the barrier (independent of LDS):
    const size_t ebase = (size_t)(b * MM) * EE + (size_t)t;
    float eA[16], eB[16];
    #pragma unroll
    for (int i = 0; i < 16; ++i) eA[i] = emb[ebase + (size_t)i * EE];
    #pragma unroll
    for (int i = 0; i < 16; ++i) eB[i] = emb[ebase + (size_t)(16 + i) * EE];

    // LDS writes, single barrier:
    #pragma unroll
    for (int it = 0; it < 2; ++it)
        S[gjj[it]][gm[it]] = (gbz[it] > tb) ? 0.0f : gv[it] * 1e-3f;
    if (t < JH) {
        aj[t] = fmaxf(al - tb, 0.0f) * 1e-3f;
        rj[t] = rl;
    }
    __syncthreads();

    float acc[JH];
    #pragma unroll
    for (int j = 0; j < JH; ++j) acc[j] = 0.0f;

    #define COMP(EREG, C)                                                  \
        _Pragma("unroll")                                                  \
        for (int j = 0; j < JH; ++j) {                                     \
            const float4* S4 = reinterpret_cast<const float4*>(&S[j][(C) * 16]); \
            _Pragma("unroll")                                              \
            for (int m4 = 0; m4 < 4; ++m4) {                               \
                const float4 s = S4[m4];                                   \
                acc[j] = fmaf(s.x, EREG[4 * m4 + 0], acc[j]);              \
                acc[j] = fmaf(s.y, EREG[4 * m4 + 1], acc[j]);              \
                acc[j] = fmaf(s.z, EREG[4 * m4 + 2], acc[j]);              \
                acc[j] = fmaf(s.w, EREG[4 * m4 + 3], acc[j]);              \
            }                                                              \
        }

    COMP(eA, 0);
    #pragma unroll
    for (int i = 0; i < 16; ++i) eA[i] = emb[ebase + (size_t)(32 + i) * EE];
    COMP(eB, 1);
    #pragma unroll
    for (int i = 0; i < 16; ++i) eB[i] = emb[ebase + (size_t)(48 + i) * EE];
    COMP(eA, 2);
    COMP(eB, 3);
    #undef COMP

    // ---- epilogue: stores grouped by output segment ----
    const size_t SZ   = (size_t)BS * JJ * EE;                 // 2097152
    const size_t base = (size_t)(b * JJ + jh * JH) * EE + (size_t)t;

    #pragma unroll
    for (int j = 0; j < JH; ++j)
        out[base + (size_t)j * EE] =
            fmaf(aj[j], w0a, fmaf(rj[j], w1a, we0 * acc[j]));
    #pragma unroll
    for (int j = 0; j < JH; ++j)
        out[SZ + base + (size_t)j * EE] =
            fmaf(aj[j], w0b, fmaf(rj[j], w1b, we1 * acc[j]));
    #pragma unroll
    for (int j = 0; j < JH; ++j)
        out[2 * SZ + base + (size_t)j * EE] =
            fmaf(aj[j], w0c, fmaf(rj[j], w1c, we2 * acc[j]));
}

extern "C" void kernel_launch(void* const* d_in, const int* in_sizes, int n_in,
                              void* d_out, int out_size, void* d_ws, size_t ws_size,
                              hipStream_t stream) {
    const float* lbs   = (const float*)d_in[0];
    const float* time_ = (const float*)d_in[1];
    const float* isr   = (const float*)d_in[2];
    const float* proc  = (const float*)d_in[3];
    const float* busy  = (const float*)d_in[4];
    const float* emb   = (const float*)d_in[5];
    const float* Wn    = (const float*)d_in[6];
    const float* We    = (const float*)d_in[7];
    const int*   nop   = (const int*)d_in[8];
    float* out = (float*)d_out;

    jssp_kernel<<<dim3(BS * (JJ / JH)), dim3(256), 0, stream>>>(
        lbs, time_, isr, proc, busy, emb, Wn, We, nop, out);
}